// Round 16
// baseline (35.760 us; speedup 1.0000x reference)
//
#include <hip/hip_runtime.h>

#define S_LEN 1024
#define D_TOT 512
#define D_E   448

typedef short bf16x8 __attribute__((ext_vector_type(8)));
typedef float f32x4  __attribute__((ext_vector_type(4)));
typedef unsigned short u16;

__device__ __forceinline__ float frcp(float x) {
  float r; asm("v_rcp_f32 %0, %1" : "=v"(r) : "v"(x)); return r;
}

__device__ __forceinline__ float wave_sum64(float v) {
#pragma unroll
  for (int o = 32; o > 0; o >>= 1) v += __shfl_xor(v, o);
  return v;
}

__device__ __forceinline__ u16 bf16rne(float f) {
  unsigned u = __builtin_bit_cast(unsigned, f);
  return (u16)((u + 0x7fffu + ((u >> 16) & 1u)) >> 16);
}

__device__ __forceinline__ uint4 rne8(float4 a, float4 b) {
  uint4 h;
  h.x = (unsigned)bf16rne(a.x) | ((unsigned)bf16rne(a.y)<<16);
  h.y = (unsigned)bf16rne(a.z) | ((unsigned)bf16rne(a.w)<<16);
  h.z = (unsigned)bf16rne(b.x) | ((unsigned)bf16rne(b.y)<<16);
  h.w = (unsigned)bf16rne(b.z) | ((unsigned)bf16rne(b.w)<<16);
  return h;
}

#define MFMA1(ACC)                                                                              \
  _Pragma("unroll") for (int i_ = 0; i_ < 2; ++i_)                                              \
  _Pragma("unroll") for (int j_ = 0; j_ < 2; ++j_)                                              \
    ACC[i_][j_] = __builtin_amdgcn_mfma_f32_16x16x32_bf16(fAh[i_], fBh[j_], ACC[i_][j_],0,0,0);

// ================= qk: q/k = x @ W.T + b (hi-only MFMA1), z in {0,1} =================
__global__ __launch_bounds__(512,4) void qk_mfma(
    const float* __restrict__ x,
    const float* __restrict__ wq, const float* __restrict__ bq,
    const float* __restrict__ wk, const float* __restrict__ bk,
    u16* __restrict__ Qch, u16* __restrict__ Kch,
    float* __restrict__ qnpart, float* __restrict__ knpart,
    float* __restrict__ uh2a, float* __restrict__ vh2a)
{
  __shared__ __align__(16) u16 stage[2][10240];
  float* fbuf = (float*)stage;
  const int z = blockIdx.z;
  const float* W    = z ? wk : wq;
  const float* bias = z ? bk : bq;
  const int mBase = blockIdx.y << 6, nBase = blockIdx.x << 6;
  const int t = threadIdx.x, lane = t & 63, wave = t >> 6;
  const int kg = t >> 8, sub = t & 255;
  const int srow = sub >> 2, scol = (sub & 3) << 3;
  const int kgw = wave >> 2, wr = (wave >> 1) & 1, wc = wave & 1;

  const float* Ag = x + (size_t)(mBase + srow) * D_TOT + scol + kg * 256;
  const float* Bg = W + (size_t)(nBase + srow) * D_TOT + scol + kg * 256;

  const int sb = kg * 5120 + srow * 40 + scol;
  const int fa = kgw * 5120 + (wr * 32 + (lane & 15)) * 40 + ((lane >> 4) << 3);
  const int fb = kgw * 5120 + 2560 + (wc * 32 + (lane & 15)) * 40 + ((lane >> 4) << 3);

  float4 a0 = *(const float4*)Ag, a1 = *(const float4*)(Ag + 4);
  float4 b0 = *(const float4*)Bg, b1 = *(const float4*)(Bg + 4);
  *(uint4*)&stage[0][sb       ] = rne8(a0,a1);
  *(uint4*)&stage[0][sb + 2560] = rne8(b0,b1);
  a0 = *(const float4*)(Ag + 32); a1 = *(const float4*)(Ag + 36);
  b0 = *(const float4*)(Bg + 32); b1 = *(const float4*)(Bg + 36);

  f32x4 zero = {0.f,0.f,0.f,0.f};
  f32x4 acc[2][2] = {{zero,zero},{zero,zero}};
#pragma unroll
  for (int r = 0; r < 8; ++r) {
    __syncthreads();
    const u16* bufr = stage[r & 1];
    bf16x8 fAh[2], fBh[2];
#pragma unroll
    for (int i = 0; i < 2; ++i) {
      fAh[i] = *(const bf16x8*)&bufr[fa + i*640];
      fBh[i] = *(const bf16x8*)&bufr[fb + i*640];
    }
    if (r + 1 < 8) {
      u16* bufw = stage[(r + 1) & 1];
      *(uint4*)&bufw[sb       ] = rne8(a0,a1);
      *(uint4*)&bufw[sb + 2560] = rne8(b0,b1);
      if (r + 2 < 8) {
        const int o = (r + 2) * 32;
        a0 = *(const float4*)(Ag + o); a1 = *(const float4*)(Ag + o + 4);
        b0 = *(const float4*)(Bg + o); b1 = *(const float4*)(Bg + o + 4);
      }
    }
    MFMA1(acc);
  }

  __syncthreads();
  {
    const int r0 = wr*32 + ((lane>>4)<<2);
    const int c0 = wc*32 + (lane&15);
#pragma unroll
    for (int i = 0; i < 2; ++i)
#pragma unroll
      for (int j = 0; j < 2; ++j)
#pragma unroll
        for (int g = 0; g < 4; ++g)
          fbuf[kgw*4352 + (r0 + i*16 + g)*68 + c0 + j*16] = acc[i][j][g];
  }
  __syncthreads();
  const int erow = wave << 3;
  float val[8];
  {
    const float b = bias[nBase + lane];
#pragma unroll
    for (int r = 0; r < 8; ++r)
      val[r] = fbuf[(erow+r)*68 + lane] + fbuf[4352 + (erow+r)*68 + lane] + b;
  }

  u16* Ch = z ? Kch : Qch;
  float* np_ = z ? knpart : qnpart;
  float* u2a = z ? vh2a  : uh2a;
  if (blockIdx.x < 7) {
#pragma unroll
    for (int r = 0; r < 8; ++r) {
      const int s = mBase + erow + r;
      Ch[(size_t)s*D_TOT + nBase + lane] = bf16rne(val[r]);
      float p = wave_sum64(val[r]*val[r]);
      if (lane == 0) np_[s*8 + blockIdx.x] = p;
    }
  } else {
#pragma unroll
    for (int r = 0; r < 8; ++r) {
      const int s = mBase + erow + r;
      float n2 = wave_sum64(val[r]*val[r]);
      float nn = sqrtf(n2);
      float n  = fmaxf(nn, 1e-5f);
      float e2n = __expf(2.f*n);
      float th  = 1.f - 2.f*frcp(e2n + 1.f);
      float rn  = frcp(n);
      float pn  = th * nn * rn;
      float scale = fminf(0.999f * frcp(fmaxf(pn, 1e-5f)), 1.f);
      float u = th * rn * scale * val[r];
      float un = pn * scale;
      Ch[(size_t)s*D_TOT + nBase + lane] = bf16rne(u);
      if (lane == 0) u2a[s] = un*un;
    }
  }
}

// ================= score_v: blocks 0..255 = score; 256..383 = v = x@wv.T+bv (transposed hi) =================
__global__ __launch_bounds__(512,4) void score_v(
    const u16* __restrict__ Qch, const u16* __restrict__ Kch,
    const float* __restrict__ qnpart, const float* __restrict__ knpart,
    const float* __restrict__ uh2a, const float* __restrict__ vh2a,
    const float* __restrict__ alpha_u,
    const float* __restrict__ x,
    const float* __restrict__ wv, const float* __restrict__ bv,
    u16* __restrict__ Eh, float* __restrict__ rowpart,
    u16* __restrict__ vTh)
{
  __shared__ __align__(16) char shm_[69632];
  __shared__ float rowscal[256];
  u16* stg = (u16*)shm_;
  float* fbuf = (float*)shm_;
  const int bid = blockIdx.x;
  const int t = threadIdx.x, lane = t & 63, wave = t >> 6;
  const int kg = t >> 8, sub = t & 255;
  const int srow = sub >> 2, scol = (sub & 3) << 3;
  const int kgw = wave >> 2, wr = (wave >> 1) & 1, wc = wave & 1;

  if (bid < 256) {
    // ---------------- score (round-15 verbatim, flattened grid) ----------------
    const int nx = bid & 15;
    const int mBase = (bid >> 4) << 6, nBase = nx << 6;
    if (t < 64) {
      float s_ = 0.f;
#pragma unroll
      for (int c = 0; c < 7; ++c) s_ += qnpart[(mBase+t)*8 + c];
      rowscal[t] = s_;
    } else if (t < 128) {
      float s_ = 0.f;
#pragma unroll
      for (int c = 0; c < 7; ++c) s_ += knpart[(nBase+t-64)*8 + c];
      rowscal[t] = s_;
    } else if (t < 192) rowscal[t] = uh2a[mBase + t - 128];
    else if (t < 256)   rowscal[t] = vh2a[nBase + t - 192];

    const u16* Agh = Qch + (size_t)(mBase+srow)*D_TOT + scol;
    const u16* Bgh = Kch + (size_t)(nBase+srow)*D_TOT + scol;

    const int sb  = kg * 5120 + srow * 40 + scol;
    const int fa  = kgw * 5120 + (wr * 32 + (lane & 15)) * 40 + ((lane >> 4) << 3);
    const int fbh = kgw * 5120 + 2560 + (wc * 32 + (lane & 15)) * 40 + ((lane >> 4) << 3);

    int kb = kg * 224;
    uint4 rAh = *(const uint4*)(Agh + kb);
    uint4 rBh = *(const uint4*)(Bgh + kb);
    *(uint4*)&stg[sb       ] = rAh;
    *(uint4*)&stg[sb + 2560] = rBh;
    kb = kg * 224 + 32;
    rAh = *(const uint4*)(Agh + kb);
    rBh = *(const uint4*)(Bgh + kb);

    f32x4 zero = {0.f,0.f,0.f,0.f};
    f32x4 accE[2][2] = {{zero,zero},{zero,zero}};
    f32x4 accH[2][2] = {{zero,zero},{zero,zero}};
#pragma unroll
    for (int r = 0; r < 8; ++r) {
      __syncthreads();
      const u16* bufr = stg + (r & 1) * 10240;
      bf16x8 fAh[2], fBh[2];
#pragma unroll
      for (int i = 0; i < 2; ++i) {
        fAh[i] = *(const bf16x8*)&bufr[fa  + i*640];
        fBh[i] = *(const bf16x8*)&bufr[fbh + i*640];
      }
      if (r + 1 < 8) {
        u16* bufw = stg + ((r + 1) & 1) * 10240;
        *(uint4*)&bufw[sb       ] = rAh;
        *(uint4*)&bufw[sb + 2560] = rBh;
        if (r + 2 < 8) {
          const int o = (r + 2 < 7) ? (kg*224 + (r+2)*32) : (448 + kg*32);
          rAh = *(const uint4*)(Agh + o);
          rBh = *(const uint4*)(Bgh + o);
        }
      }
      if (r < 7) { MFMA1(accE) } else { MFMA1(accH) }
    }

    __syncthreads();
    {
      const int r0 = wr*32 + ((lane>>4)<<2);
      const int c0 = wc*32 + (lane&15);
#pragma unroll
      for (int i = 0; i < 2; ++i)
#pragma unroll
        for (int j = 0; j < 2; ++j)
#pragma unroll
          for (int g = 0; g < 4; ++g) {
            fbuf[       kgw*4352 + (r0 + i*16 + g)*68 + c0 + j*16] = accE[i][j][g];
            fbuf[8704 + kgw*4352 + (r0 + i*16 + g)*68 + c0 + j*16] = accH[i][j][g];
          }
    }
    __syncthreads();
    const int erow = wave << 3;
    float eE[8], eH[8];
#pragma unroll
    for (int r = 0; r < 8; ++r) {
      eE[r] = fbuf[(erow+r)*68 + lane] + fbuf[4352 + (erow+r)*68 + lane];
      eH[r] = fbuf[8704 + (erow+r)*68 + lane] + fbuf[8704 + 4352 + (erow+r)*68 + lane];
    }

    const float alpha = __logf(1.f + __expf(alpha_u[0]));
    const float inv_s = 0.04419417382415922f;
    const float knl = rowscal[64 + lane], v2 = rowscal[192 + lane];
#pragma unroll
    for (int r = 0; r < 8; ++r) {
      const int s = mBase + erow + r;
      const float qns = rowscal[erow + r], u2 = rowscal[128 + erow + r];
      float de   = qns + knl - 2.f * eE[r];
      float dH   = eH[r];
      float Ac   = 1.f - 2.f*dH + v2;
      float Bc   = 1.f - u2;
      float num2 = Ac*Ac*u2 + Bc*Bc*v2 - 2.f*Ac*Bc*dH;
      float den  = fmaxf(1.f - 2.f*dH + u2*v2, 1e-5f);
      float frac = sqrtf(fmaxf(num2, 0.f)) * frcp(den);
      float nrm  = fminf(frac, 0.999f);
      float dh_  = __logf((1.f + nrm) * frcp(1.f - nrm));
      float dist = de + alpha * dh_ * dh_;
      float lg   = fminf(fmaxf(-dist * inv_s, -50.f), 0.f);
      float e    = __expf(lg);
      Eh[(size_t)s*S_LEN + nBase + lane] = bf16rne(e);
      float rs = wave_sum64(e);
      if (lane == 0) rowpart[s*16 + nx] = rs;
    }
  } else {
    // ---------------- v = x @ wv.T + bv, stored transposed hi-only ----------------
    const int b2 = bid - 256;
    const int mBase = (b2 >> 3) << 6, nBase = (b2 & 7) << 6;

    const float* Ag = x  + (size_t)(mBase + srow) * D_TOT + scol + kg * 256;
    const float* Bg = wv + (size_t)(nBase + srow) * D_TOT + scol + kg * 256;

    const int sb = kg * 5120 + srow * 40 + scol;
    const int fa = kgw * 5120 + (wr * 32 + (lane & 15)) * 40 + ((lane >> 4) << 3);
    const int fb = kgw * 5120 + 2560 + (wc * 32 + (lane & 15)) * 40 + ((lane >> 4) << 3);

    float4 a0 = *(const float4*)Ag, a1 = *(const float4*)(Ag + 4);
    float4 b0 = *(const float4*)Bg, b1 = *(const float4*)(Bg + 4);
    *(uint4*)&stg[sb       ] = rne8(a0,a1);
    *(uint4*)&stg[sb + 2560] = rne8(b0,b1);
    a0 = *(const float4*)(Ag + 32); a1 = *(const float4*)(Ag + 36);
    b0 = *(const float4*)(Bg + 32); b1 = *(const float4*)(Bg + 36);

    f32x4 zero = {0.f,0.f,0.f,0.f};
    f32x4 acc[2][2] = {{zero,zero},{zero,zero}};
#pragma unroll
    for (int r = 0; r < 8; ++r) {
      __syncthreads();
      const u16* bufr = stg + (r & 1) * 10240;
      bf16x8 fAh[2], fBh[2];
#pragma unroll
      for (int i = 0; i < 2; ++i) {
        fAh[i] = *(const bf16x8*)&bufr[fa + i*640];
        fBh[i] = *(const bf16x8*)&bufr[fb + i*640];
      }
      if (r + 1 < 8) {
        u16* bufw = stg + ((r + 1) & 1) * 10240;
        *(uint4*)&bufw[sb       ] = rne8(a0,a1);
        *(uint4*)&bufw[sb + 2560] = rne8(b0,b1);
        if (r + 2 < 8) {
          const int o = (r + 2) * 32;
          a0 = *(const float4*)(Ag + o); a1 = *(const float4*)(Ag + o + 4);
          b0 = *(const float4*)(Bg + o); b1 = *(const float4*)(Bg + o + 4);
        }
      }
      MFMA1(acc);
    }

    __syncthreads();
    {
      const int r0 = wr*32 + ((lane>>4)<<2);
      const int c0 = wc*32 + (lane&15);
#pragma unroll
      for (int i = 0; i < 2; ++i)
#pragma unroll
        for (int j = 0; j < 2; ++j)
#pragma unroll
          for (int g = 0; g < 4; ++g)
            fbuf[kgw*4352 + (r0 + i*16 + g)*68 + c0 + j*16] = acc[i][j][g];
    }
    __syncthreads();
    const int erow = wave << 3;
    u16 hh[8];
    {
      const float b = bv[nBase + lane];
#pragma unroll
      for (int r = 0; r < 8; ++r)
        hh[r] = bf16rne(fbuf[(erow+r)*68 + lane] + fbuf[4352 + (erow+r)*68 + lane] + b);
    }
    const size_t off = (size_t)(nBase + lane) * S_LEN + mBase + erow;
    ushort4 p0{hh[0],hh[1],hh[2],hh[3]}, p1{hh[4],hh[5],hh[6],hh[7]};
    *(ushort4*)(vTh + off) = p0; *(ushort4*)(vTh + off + 4) = p1;
  }
}

// ================= av (round-15 verbatim): out1 = diag(rinv)*(E @ vT^T), MFMA1, dbuf =================
__global__ __launch_bounds__(512,4) void av_mfma(
    const u16* __restrict__ Eh, const u16* __restrict__ vTh,
    const float* __restrict__ rowpart,
    u16* __restrict__ out1h)
{
  __shared__ __align__(16) u16 stage[2][15360];
  __shared__ float rinvl[32];
  float* fbuf = (float*)stage;
  const int t = threadIdx.x, lane = t & 63, wave = t >> 6;
  const int mBase = blockIdx.y << 5, nBase = blockIdx.x << 6;
  if (t < 32) {
    float s_ = 0.f;
#pragma unroll
    for (int c = 0; c < 16; ++c) s_ += rowpart[(mBase+t)*16 + c];
    rinvl[t] = 1.f / s_;
  }
  const int kg = t >> 7, sub = t & 127;
  const int arow = sub >> 2, acol = (sub & 3) << 3;
  const int brow0 = sub >> 2, brow1 = 32 + (sub >> 2), bcol = (sub & 3) << 3;
  const int kgw = wave >> 1, wc = wave & 1;

  const u16* Ag = Eh  + (size_t)(mBase+arow)*S_LEN + kg*256 + acol;
  const u16* B0 = vTh + (size_t)(nBase+brow0)*S_LEN + kg*256 + bcol;
  const u16* B1 = vTh + (size_t)(nBase+brow1)*S_LEN + kg*256 + bcol;

  const int sA  = kg*3840 + arow*40 + acol;
  const int sB0 = kg*3840 + 1280 + brow0*40 + bcol;
  const int sB1 = kg*3840 + 1280 + brow1*40 + bcol;
  const int fa  = kgw*3840 + (lane&15)*40 + ((lane>>4)<<3);
  const int fb  = kgw*3840 + 1280 + (wc*32 + (lane&15))*40 + ((lane>>4)<<3);

  uint4 rA = *(const uint4*)Ag;
  uint4 rb0 = *(const uint4*)B0, rb1 = *(const uint4*)B1;
  *(uint4*)&stage[0][sA ] = rA;
  *(uint4*)&stage[0][sB0] = rb0; *(uint4*)&stage[0][sB1] = rb1;
  rA = *(const uint4*)(Ag + 32);
  rb0 = *(const uint4*)(B0 + 32); rb1 = *(const uint4*)(B1 + 32);

  f32x4 zero = {0.f,0.f,0.f,0.f};
  f32x4 acc[2][2] = {{zero,zero},{zero,zero}};
#pragma unroll
  for (int r = 0; r < 8; ++r) {
    __syncthreads();
    const u16* bufr = stage[r & 1];
    bf16x8 fAh[2], fBh[2];
#pragma unroll
    for (int i = 0; i < 2; ++i) {
      fAh[i] = *(const bf16x8*)&bufr[fa + i*640];
      fBh[i] = *(const bf16x8*)&bufr[fb + i*640];
    }
    if (r + 1 < 8) {
      u16* bufw = stage[(r + 1) & 1];
      *(uint4*)&bufw[sA ] = rA;
      *(uint4*)&bufw[sB0] = rb0; *(uint4*)&bufw[sB1] = rb1;
      if (r + 2 < 8) {
        const int o = (r + 2) * 32;
        rA = *(const uint4*)(Ag + o);
        rb0 = *(const uint4*)(B0 + o); rb1 = *(const uint4*)(B1 + o);
      }
    }
    MFMA1(acc);
  }

  __syncthreads();
  {
    const int r0 = (lane>>4)<<2;
    const int c0 = wc*32 + (lane&15);
#pragma unroll
    for (int i = 0; i < 2; ++i)
#pragma unroll
      for (int j = 0; j < 2; ++j)
#pragma unroll
        for (int g = 0; g < 4; ++g)
          fbuf[kgw*2176 + (r0 + i*16 + g)*68 + c0 + j*16] = acc[i][j][g];
  }
  __syncthreads();
  const int erow = wave << 2;
#pragma unroll
  for (int r = 0; r < 4; ++r) {
    const int row = erow + r;
    float e = fbuf[row*68 + lane] + fbuf[2176 + row*68 + lane]
            + fbuf[4352 + row*68 + lane] + fbuf[6528 + row*68 + lane];
    float v_ = e * rinvl[row];
    const int s = mBase + row;
    out1h[(size_t)s*D_TOT + nBase + lane] = bf16rne(v_);
  }
}

// ================= final (round-15 verbatim): out = out1h @ wo.T + bo =================
__global__ __launch_bounds__(512,4) void final_mfma(
    const u16* __restrict__ out1h,
    const float* __restrict__ wo, const float* __restrict__ bo,
    float* __restrict__ out)
{
  __shared__ __align__(16) u16 stage[2][15360];
  float* fbuf = (float*)stage;
  const int t = threadIdx.x, lane = t & 63, wave = t >> 6;
  const int mBase = blockIdx.y << 5, nBase = blockIdx.x << 6;
  const int kg = t >> 7, sub = t & 127;
  const int arow = sub >> 2, acol = (sub & 3) << 3;
  const int brow0 = sub >> 2, brow1 = 32 + (sub >> 2), bcol = (sub & 3) << 3;
  const int kgw = wave >> 1, wc = wave & 1;

  const u16*   Ag = out1h + (size_t)(mBase+arow)*D_TOT + kg*128 + acol;
  const float* B0 = wo + (size_t)(nBase+brow0)*D_TOT + kg*128 + bcol;
  const float* B1 = wo + (size_t)(nBase+brow1)*D_TOT + kg*128 + bcol;

  const int sA  = kg*3840 + arow*40 + acol;
  const int sB0 = kg*3840 + 1280 + brow0*40 + bcol;
  const int sB1 = kg*3840 + 1280 + brow1*40 + bcol;
  const int fa  = kgw*3840 + (lane&15)*40 + ((lane>>4)<<3);
  const int fb  = kgw*3840 + 1280 + (wc*32 + (lane&15))*40 + ((lane>>4)<<3);

  uint4 rA = *(const uint4*)Ag;
  float4 b00 = *(const float4*)B0, b01 = *(const float4*)(B0 + 4);
  float4 b10 = *(const float4*)B1, b11 = *(const float4*)(B1 + 4);
  *(uint4*)&stage[0][sA ] = rA;
  *(uint4*)&stage[0][sB0] = rne8(b00,b01);
  *(uint4*)&stage[0][sB1] = rne8(b10,b11);
  rA = *(const uint4*)(Ag + 32);
  b00 = *(const float4*)(B0 + 32); b01 = *(const float4*)(B0 + 36);
  b10 = *(const float4*)(B1 + 32); b11 = *(const float4*)(B1 + 36);

  f32x4 zero = {0.f,0.f,0.f,0.f};
  f32x4 acc[2][2] = {{zero,zero},{zero,zero}};
#pragma unroll
  for (int r = 0; r < 4; ++r) {
    __syncthreads();
    const u16* bufr = stage[r & 1];
    bf16x8 fAh[2], fBh[2];
#pragma unroll
    for (int i = 0; i < 2; ++i) {
      fAh[i] = *(const bf16x8*)&bufr[fa + i*640];
      fBh[i] = *(const bf16x8*)&bufr[fb + i*640];
    }
    if (r + 1 < 4) {
      u16* bufw = stage[(r + 1) & 1];
      *(uint4*)&bufw[sA ] = rA;
      *(uint4*)&bufw[sB0] = rne8(b00,b01);
      *(uint4*)&bufw[sB1] = rne8(b10,b11);
      if (r + 2 < 4) {
        const int o = (r + 2) * 32;
        rA = *(const uint4*)(Ag + o);
        b00 = *(const float4*)(B0 + o); b01 = *(const float4*)(B0 + o + 4);
        b10 = *(const float4*)(B1 + o); b11 = *(const float4*)(B1 + o + 4);
      }
    }
    MFMA1(acc);
  }

  __syncthreads();
  {
    const int r0 = (lane>>4)<<2;
    const int c0 = wc*32 + (lane&15);
#pragma unroll
    for (int i = 0; i < 2; ++i)
#pragma unroll
      for (int j = 0; j < 2; ++j)
#pragma unroll
        for (int g = 0; g < 4; ++g)
          fbuf[kgw*2176 + (r0 + i*16 + g)*68 + c0 + j*16] = acc[i][j][g];
  }
  __syncthreads();
  const int erow = wave << 2;
  const float b = bo[nBase + lane];
#pragma unroll
  for (int r = 0; r < 4; ++r) {
    const int row = erow + r;
    float e = fbuf[row*68 + lane] + fbuf[2176 + row*68 + lane]
            + fbuf[4352 + row*68 + lane] + fbuf[6528 + row*68 + lane];
    out[(size_t)(mBase+row)*D_TOT + nBase + lane] = e + b;
  }
}

extern "C" void kernel_launch(void* const* d_in, const int* in_sizes, int n_in,
                              void* d_out, int out_size, void* d_ws, size_t ws_size,
                              hipStream_t stream)
{
  const float* x   = (const float*)d_in[0];
  const float* wq  = (const float*)d_in[1];
  const float* bq  = (const float*)d_in[2];
  const float* wk  = (const float*)d_in[3];
  const float* bk  = (const float*)d_in[4];
  const float* wv  = (const float*)d_in[5];
  const float* bv  = (const float*)d_in[6];
  const float* wo  = (const float*)d_in[7];
  const float* bo  = (const float*)d_in[8];
  const float* alpha_u = (const float*)d_in[9];
  float* out = (float*)d_out;

  u16* U = (u16*)d_ws;
  u16* Qch   = U + 0;
  u16* Kch   = U + 524288;
  u16* vTh   = U + 1048576;
  u16* Eh    = U + 1572864;
  u16* out1h = U + 2621440;
  float* F = (float*)(U + 3145728);
  float* qnpart  = F;
  float* knpart  = F + 8192;
  float* uh2a    = F + 16384;
  float* vh2a    = F + 17408;
  float* rowpart = F + 18432;

  qk_mfma<<<dim3(8,16,2), 512, 0, stream>>>(x, wq,bq, wk,bk,
      Qch, Kch, qnpart, knpart, uh2a, vh2a);
  score_v<<<dim3(384), 512, 0, stream>>>(Qch, Kch,
      qnpart, knpart, uh2a, vh2a, alpha_u, x, wv, bv, Eh, rowpart, vTh);
  av_mfma<<<dim3(8,32), 512, 0, stream>>>(Eh, vTh, rowpart, out1h);
  final_mfma<<<dim3(8,32), 512, 0, stream>>>(out1h, wo, bo, out);
}

// Round 17
// 34.669 us; speedup vs baseline: 1.0315x; 1.0315x over previous
//
#include <hip/hip_runtime.h>

#define S_LEN 1024
#define D_TOT 512
#define D_E   448

typedef short bf16x8 __attribute__((ext_vector_type(8)));
typedef float f32x4  __attribute__((ext_vector_type(4)));
typedef unsigned short u16;

__device__ __forceinline__ float frcp(float x) {
  float r; asm("v_rcp_f32 %0, %1" : "=v"(r) : "v"(x)); return r;
}

__device__ __forceinline__ float wave_sum64(float v) {
#pragma unroll
  for (int o = 32; o > 0; o >>= 1) v += __shfl_xor(v, o);
  return v;
}

__device__ __forceinline__ u16 bf16rne(float f) {
  unsigned u = __builtin_bit_cast(unsigned, f);
  return (u16)((u + 0x7fffu + ((u >> 16) & 1u)) >> 16);
}

__device__ __forceinline__ uint4 rne8(float4 a, float4 b) {
  uint4 h;
  h.x = (unsigned)bf16rne(a.x) | ((unsigned)bf16rne(a.y)<<16);
  h.y = (unsigned)bf16rne(a.z) | ((unsigned)bf16rne(a.w)<<16);
  h.z = (unsigned)bf16rne(b.x) | ((unsigned)bf16rne(b.y)<<16);
  h.w = (unsigned)bf16rne(b.z) | ((unsigned)bf16rne(b.w)<<16);
  return h;
}

#define MFMA1(ACC)                                                                              \
  _Pragma("unroll") for (int i_ = 0; i_ < 2; ++i_)                                              \
  _Pragma("unroll") for (int j_ = 0; j_ < 2; ++j_)                                              \
    ACC[i_][j_] = __builtin_amdgcn_mfma_f32_16x16x32_bf16(fAh[i_], fBh[j_], ACC[i_][j_],0,0,0);

// ================= QKV: q/k/v = x @ W.T + b (all hi-only, MFMA1) =================
// 64x64 tile, 8 waves = 2(kg) x 2(wr) x 2(wc), BK=32, dbuf LDS 40960B.
__global__ __launch_bounds__(512,4) void qkv_mfma(
    const float* __restrict__ x,
    const float* __restrict__ wq, const float* __restrict__ bq,
    const float* __restrict__ wk, const float* __restrict__ bk,
    const float* __restrict__ wv, const float* __restrict__ bv,
    u16* __restrict__ Qch, u16* __restrict__ Kch, u16* __restrict__ vTh,
    float* __restrict__ qnpart, float* __restrict__ knpart,
    float* __restrict__ uh2a, float* __restrict__ vh2a)
{
  __shared__ __align__(16) u16 stage[2][10240];   // per buf: [2 kg][A 2560 | B 2560]
  float* fbuf = (float*)stage;                    // [2][64][68] overlay
  const int z = blockIdx.z;
  const float* W; const float* bias;
  if (z == 0)      { W = wq; bias = bq; }
  else if (z == 1) { W = wk; bias = bk; }
  else             { W = wv; bias = bv; }
  const int mBase = blockIdx.y << 6, nBase = blockIdx.x << 6;
  const int t = threadIdx.x, lane = t & 63, wave = t >> 6;
  const int kg = t >> 8, sub = t & 255;
  const int srow = sub >> 2, scol = (sub & 3) << 3;
  const int kgw = wave >> 2, wr = (wave >> 1) & 1, wc = wave & 1;

  const float* Ag = x + (size_t)(mBase + srow) * D_TOT + scol + kg * 256;
  const float* Bg = W + (size_t)(nBase + srow) * D_TOT + scol + kg * 256;

  const int sb = kg * 5120 + srow * 40 + scol;
  const int fa = kgw * 5120 + (wr * 32 + (lane & 15)) * 40 + ((lane >> 4) << 3);
  const int fb = kgw * 5120 + 2560 + (wc * 32 + (lane & 15)) * 40 + ((lane >> 4) << 3);

  float4 a0 = *(const float4*)Ag, a1 = *(const float4*)(Ag + 4);
  float4 b0 = *(const float4*)Bg, b1 = *(const float4*)(Bg + 4);
  *(uint4*)&stage[0][sb       ] = rne8(a0,a1);
  *(uint4*)&stage[0][sb + 2560] = rne8(b0,b1);
  a0 = *(const float4*)(Ag + 32); a1 = *(const float4*)(Ag + 36);
  b0 = *(const float4*)(Bg + 32); b1 = *(const float4*)(Bg + 36);

  f32x4 zero = {0.f,0.f,0.f,0.f};
  f32x4 acc[2][2] = {{zero,zero},{zero,zero}};
#pragma unroll
  for (int r = 0; r < 8; ++r) {
    __syncthreads();
    const u16* bufr = stage[r & 1];
    bf16x8 fAh[2], fBh[2];
#pragma unroll
    for (int i = 0; i < 2; ++i) {
      fAh[i] = *(const bf16x8*)&bufr[fa + i*640];
      fBh[i] = *(const bf16x8*)&bufr[fb + i*640];
    }
    if (r + 1 < 8) {
      u16* bufw = stage[(r + 1) & 1];
      *(uint4*)&bufw[sb       ] = rne8(a0,a1);
      *(uint4*)&bufw[sb + 2560] = rne8(b0,b1);
      if (r + 2 < 8) {
        const int o = (r + 2) * 32;
        a0 = *(const float4*)(Ag + o); a1 = *(const float4*)(Ag + o + 4);
        b0 = *(const float4*)(Bg + o); b1 = *(const float4*)(Bg + o + 4);
      }
    }
    MFMA1(acc);
  }

  __syncthreads();
  {
    const int r0 = wr*32 + ((lane>>4)<<2);
    const int c0 = wc*32 + (lane&15);
#pragma unroll
    for (int i = 0; i < 2; ++i)
#pragma unroll
      for (int j = 0; j < 2; ++j)
#pragma unroll
        for (int g = 0; g < 4; ++g)
          fbuf[kgw*4352 + (r0 + i*16 + g)*68 + c0 + j*16] = acc[i][j][g];
  }
  __syncthreads();
  const int erow = wave << 3;
  float val[8];
  {
    const float b = bias[nBase + lane];
#pragma unroll
    for (int r = 0; r < 8; ++r)
      val[r] = fbuf[(erow+r)*68 + lane] + fbuf[4352 + (erow+r)*68 + lane] + b;
  }

  if (z == 2) {
    u16 hh[8];
#pragma unroll
    for (int r = 0; r < 8; ++r) hh[r] = bf16rne(val[r]);
    const size_t off = (size_t)(nBase + lane) * S_LEN + mBase + erow;
    ushort4 p0{hh[0],hh[1],hh[2],hh[3]}, p1{hh[4],hh[5],hh[6],hh[7]};
    *(ushort4*)(vTh + off) = p0; *(ushort4*)(vTh + off + 4) = p1;
  } else {
    u16* Ch = z ? Kch : Qch;
    float* np_ = z ? knpart : qnpart;
    float* u2a = z ? vh2a  : uh2a;
    if (blockIdx.x < 7) {
#pragma unroll
      for (int r = 0; r < 8; ++r) {
        const int s = mBase + erow + r;
        Ch[(size_t)s*D_TOT + nBase + lane] = bf16rne(val[r]);
        float p = wave_sum64(val[r]*val[r]);
        if (lane == 0) np_[s*8 + blockIdx.x] = p;
      }
    } else {
#pragma unroll
      for (int r = 0; r < 8; ++r) {
        const int s = mBase + erow + r;
        float n2 = wave_sum64(val[r]*val[r]);
        float nn = sqrtf(n2);
        float n  = fmaxf(nn, 1e-5f);
        float e2n = __expf(2.f*n);
        float th  = 1.f - 2.f*frcp(e2n + 1.f);
        float rn  = frcp(n);
        float pn  = th * nn * rn;
        float scale = fminf(0.999f * frcp(fmaxf(pn, 1e-5f)), 1.f);
        float u = th * rn * scale * val[r];
        float un = pn * scale;
        Ch[(size_t)s*D_TOT + nBase + lane] = bf16rne(u);
        if (lane == 0) u2a[s] = un*un;
      }
    }
  }
}

// ================= score: Q hi x K hi (MFMA1), dbuf, 64x64 tile =================
__global__ __launch_bounds__(512,4) void score_mfma(
    const u16* __restrict__ Qch, const u16* __restrict__ Kch,
    const float* __restrict__ qnpart, const float* __restrict__ knpart,
    const float* __restrict__ uh2a, const float* __restrict__ vh2a,
    const float* __restrict__ alpha_u,
    u16* __restrict__ Eh, float* __restrict__ rowpart)
{
  __shared__ __align__(16) char shm_[69632];
  __shared__ float rowscal[256];
  u16* stg = (u16*)shm_;
  float* fbuf = (float*)shm_;
  const int t = threadIdx.x, lane = t & 63, wave = t >> 6;
  const int mBase = blockIdx.y << 6, nBase = blockIdx.x << 6;
  if (t < 64) {
    float s_ = 0.f;
#pragma unroll
    for (int c = 0; c < 7; ++c) s_ += qnpart[(mBase+t)*8 + c];
    rowscal[t] = s_;
  } else if (t < 128) {
    float s_ = 0.f;
#pragma unroll
    for (int c = 0; c < 7; ++c) s_ += knpart[(nBase+t-64)*8 + c];
    rowscal[t] = s_;
  } else if (t < 192) rowscal[t] = uh2a[mBase + t - 128];
  else if (t < 256)   rowscal[t] = vh2a[nBase + t - 192];

  const int kg = t >> 8, sub = t & 255;
  const int srow = sub >> 2, scol = (sub & 3) << 3;
  const int kgw = wave >> 2, wr = (wave >> 1) & 1, wc = wave & 1;
  const u16* Agh = Qch + (size_t)(mBase+srow)*D_TOT + scol;
  const u16* Bgh = Kch + (size_t)(nBase+srow)*D_TOT + scol;

  const int sb  = kg * 5120 + srow * 40 + scol;
  const int fa  = kgw * 5120 + (wr * 32 + (lane & 15)) * 40 + ((lane >> 4) << 3);
  const int fbh = kgw * 5120 + 2560 + (wc * 32 + (lane & 15)) * 40 + ((lane >> 4) << 3);

  int kb = kg * 224;
  uint4 rAh = *(const uint4*)(Agh + kb);
  uint4 rBh = *(const uint4*)(Bgh + kb);
  *(uint4*)&stg[sb       ] = rAh;
  *(uint4*)&stg[sb + 2560] = rBh;
  kb = kg * 224 + 32;
  rAh = *(const uint4*)(Agh + kb);
  rBh = *(const uint4*)(Bgh + kb);

  f32x4 zero = {0.f,0.f,0.f,0.f};
  f32x4 accE[2][2] = {{zero,zero},{zero,zero}};
  f32x4 accH[2][2] = {{zero,zero},{zero,zero}};
#pragma unroll
  for (int r = 0; r < 8; ++r) {
    __syncthreads();
    const u16* bufr = stg + (r & 1) * 10240;
    bf16x8 fAh[2], fBh[2];
#pragma unroll
    for (int i = 0; i < 2; ++i) {
      fAh[i] = *(const bf16x8*)&bufr[fa  + i*640];
      fBh[i] = *(const bf16x8*)&bufr[fbh + i*640];
    }
    if (r + 1 < 8) {
      u16* bufw = stg + ((r + 1) & 1) * 10240;
      *(uint4*)&bufw[sb       ] = rAh;
      *(uint4*)&bufw[sb + 2560] = rBh;
      if (r + 2 < 8) {
        const int o = (r + 2 < 7) ? (kg*224 + (r+2)*32) : (448 + kg*32);
        rAh = *(const uint4*)(Agh + o);
        rBh = *(const uint4*)(Bgh + o);
      }
    }
    if (r < 7) { MFMA1(accE) } else { MFMA1(accH) }
  }

  __syncthreads();
  {
    const int r0 = wr*32 + ((lane>>4)<<2);
    const int c0 = wc*32 + (lane&15);
#pragma unroll
    for (int i = 0; i < 2; ++i)
#pragma unroll
      for (int j = 0; j < 2; ++j)
#pragma unroll
        for (int g = 0; g < 4; ++g) {
          fbuf[       kgw*4352 + (r0 + i*16 + g)*68 + c0 + j*16] = accE[i][j][g];
          fbuf[8704 + kgw*4352 + (r0 + i*16 + g)*68 + c0 + j*16] = accH[i][j][g];
        }
  }
  __syncthreads();
  const int erow = wave << 3;
  float eE[8], eH[8];
#pragma unroll
  for (int r = 0; r < 8; ++r) {
    eE[r] = fbuf[(erow+r)*68 + lane] + fbuf[4352 + (erow+r)*68 + lane];
    eH[r] = fbuf[8704 + (erow+r)*68 + lane] + fbuf[8704 + 4352 + (erow+r)*68 + lane];
  }

  const float alpha = __logf(1.f + __expf(alpha_u[0]));
  const float inv_s = 0.04419417382415922f;
  const float knl = rowscal[64 + lane], v2 = rowscal[192 + lane];
#pragma unroll
  for (int r = 0; r < 8; ++r) {
    const int s = mBase + erow + r;
    const float qns = rowscal[erow + r], u2 = rowscal[128 + erow + r];
    float de   = qns + knl - 2.f * eE[r];
    float dH   = eH[r];
    float Ac   = 1.f - 2.f*dH + v2;
    float Bc   = 1.f - u2;
    float num2 = Ac*Ac*u2 + Bc*Bc*v2 - 2.f*Ac*Bc*dH;
    float den  = fmaxf(1.f - 2.f*dH + u2*v2, 1e-5f);
    float frac = sqrtf(fmaxf(num2, 0.f)) * frcp(den);
    float nrm  = fminf(frac, 0.999f);
    float dh_  = __logf((1.f + nrm) * frcp(1.f - nrm));
    float dist = de + alpha * dh_ * dh_;
    float lg   = fminf(fmaxf(-dist * inv_s, -50.f), 0.f);
    float e    = __expf(lg);
    Eh[(size_t)s*S_LEN + nBase + lane] = bf16rne(e);
    float rs = wave_sum64(e);
    if (lane == 0) rowpart[s*16 + blockIdx.x] = rs;
  }
}

// ================= av: out1 = diag(rinv)*(E @ vT^T), MFMA1, dbuf =================
__global__ __launch_bounds__(512,4) void av_mfma(
    const u16* __restrict__ Eh, const u16* __restrict__ vTh,
    const float* __restrict__ rowpart,
    u16* __restrict__ out1h)
{
  __shared__ __align__(16) u16 stage[2][15360];
  __shared__ float rinvl[32];
  float* fbuf = (float*)stage;
  const int t = threadIdx.x, lane = t & 63, wave = t >> 6;
  const int mBase = blockIdx.y << 5, nBase = blockIdx.x << 6;
  if (t < 32) {
    float s_ = 0.f;
#pragma unroll
    for (int c = 0; c < 16; ++c) s_ += rowpart[(mBase+t)*16 + c];
    rinvl[t] = 1.f / s_;
  }
  const int kg = t >> 7, sub = t & 127;
  const int arow = sub >> 2, acol = (sub & 3) << 3;
  const int brow0 = sub >> 2, brow1 = 32 + (sub >> 2), bcol = (sub & 3) << 3;
  const int kgw = wave >> 1, wc = wave & 1;

  const u16* Ag = Eh  + (size_t)(mBase+arow)*S_LEN + kg*256 + acol;
  const u16* B0 = vTh + (size_t)(nBase+brow0)*S_LEN + kg*256 + bcol;
  const u16* B1 = vTh + (size_t)(nBase+brow1)*S_LEN + kg*256 + bcol;

  const int sA  = kg*3840 + arow*40 + acol;
  const int sB0 = kg*3840 + 1280 + brow0*40 + bcol;
  const int sB1 = kg*3840 + 1280 + brow1*40 + bcol;
  const int fa  = kgw*3840 + (lane&15)*40 + ((lane>>4)<<3);
  const int fb  = kgw*3840 + 1280 + (wc*32 + (lane&15))*40 + ((lane>>4)<<3);

  uint4 rA = *(const uint4*)Ag;
  uint4 rb0 = *(const uint4*)B0, rb1 = *(const uint4*)B1;
  *(uint4*)&stage[0][sA ] = rA;
  *(uint4*)&stage[0][sB0] = rb0; *(uint4*)&stage[0][sB1] = rb1;
  rA = *(const uint4*)(Ag + 32);
  rb0 = *(const uint4*)(B0 + 32); rb1 = *(const uint4*)(B1 + 32);

  f32x4 zero = {0.f,0.f,0.f,0.f};
  f32x4 acc[2][2] = {{zero,zero},{zero,zero}};
#pragma unroll
  for (int r = 0; r < 8; ++r) {
    __syncthreads();
    const u16* bufr = stage[r & 1];
    bf16x8 fAh[2], fBh[2];
#pragma unroll
    for (int i = 0; i < 2; ++i) {
      fAh[i] = *(const bf16x8*)&bufr[fa + i*640];
      fBh[i] = *(const bf16x8*)&bufr[fb + i*640];
    }
    if (r + 1 < 8) {
      u16* bufw = stage[(r + 1) & 1];
      *(uint4*)&bufw[sA ] = rA;
      *(uint4*)&bufw[sB0] = rb0; *(uint4*)&bufw[sB1] = rb1;
      if (r + 2 < 8) {
        const int o = (r + 2) * 32;
        rA = *(const uint4*)(Ag + o);
        rb0 = *(const uint4*)(B0 + o); rb1 = *(const uint4*)(B1 + o);
      }
    }
    MFMA1(acc);
  }

  __syncthreads();
  {
    const int r0 = (lane>>4)<<2;
    const int c0 = wc*32 + (lane&15);
#pragma unroll
    for (int i = 0; i < 2; ++i)
#pragma unroll
      for (int j = 0; j < 2; ++j)
#pragma unroll
        for (int g = 0; g < 4; ++g)
          fbuf[kgw*2176 + (r0 + i*16 + g)*68 + c0 + j*16] = acc[i][j][g];
  }
  __syncthreads();
  const int erow = wave << 2;
#pragma unroll
  for (int r = 0; r < 4; ++r) {
    const int row = erow + r;
    float e = fbuf[row*68 + lane] + fbuf[2176 + row*68 + lane]
            + fbuf[4352 + row*68 + lane] + fbuf[6528 + row*68 + lane];
    float v_ = e * rinvl[row];
    const int s = mBase + row;
    out1h[(size_t)s*D_TOT + nBase + lane] = bf16rne(v_);
  }
}

// ================= final: out = out1h @ wo.T + bo (wo hi-only, MFMA1, dbuf) =================
__global__ __launch_bounds__(512,4) void final_mfma(
    const u16* __restrict__ out1h,
    const float* __restrict__ wo, const float* __restrict__ bo,
    float* __restrict__ out)
{
  __shared__ __align__(16) u16 stage[2][15360];
  float* fbuf = (float*)stage;
  const int t = threadIdx.x, lane = t & 63, wave = t >> 6;
  const int mBase = blockIdx.y << 5, nBase = blockIdx.x << 6;
  const int kg = t >> 7, sub = t & 127;
  const int arow = sub >> 2, acol = (sub & 3) << 3;
  const int brow0 = sub >> 2, brow1 = 32 + (sub >> 2), bcol = (sub & 3) << 3;
  const int kgw = wave >> 1, wc = wave & 1;

  const u16*   Ag = out1h + (size_t)(mBase+arow)*D_TOT + kg*128 + acol;
  const float* B0 = wo + (size_t)(nBase+brow0)*D_TOT + kg*128 + bcol;
  const float* B1 = wo + (size_t)(nBase+brow1)*D_TOT + kg*128 + bcol;

  const int sA  = kg*3840 + arow*40 + acol;
  const int sB0 = kg*3840 + 1280 + brow0*40 + bcol;
  const int sB1 = kg*3840 + 1280 + brow1*40 + bcol;
  const int fa  = kgw*3840 + (lane&15)*40 + ((lane>>4)<<3);
  const int fb  = kgw*3840 + 1280 + (wc*32 + (lane&15))*40 + ((lane>>4)<<3);

  uint4 rA = *(const uint4*)Ag;
  float4 b00 = *(const float4*)B0, b01 = *(const float4*)(B0 + 4);
  float4 b10 = *(const float4*)B1, b11 = *(const float4*)(B1 + 4);
  *(uint4*)&stage[0][sA ] = rA;
  *(uint4*)&stage[0][sB0] = rne8(b00,b01);
  *(uint4*)&stage[0][sB1] = rne8(b10,b11);
  rA = *(const uint4*)(Ag + 32);
  b00 = *(const float4*)(B0 + 32); b01 = *(const float4*)(B0 + 36);
  b10 = *(const float4*)(B1 + 32); b11 = *(const float4*)(B1 + 36);

  f32x4 zero = {0.f,0.f,0.f,0.f};
  f32x4 acc[2][2] = {{zero,zero},{zero,zero}};
#pragma unroll
  for (int r = 0; r < 4; ++r) {
    __syncthreads();
    const u16* bufr = stage[r & 1];
    bf16x8 fAh[2], fBh[2];
#pragma unroll
    for (int i = 0; i < 2; ++i) {
      fAh[i] = *(const bf16x8*)&bufr[fa + i*640];
      fBh[i] = *(const bf16x8*)&bufr[fb + i*640];
    }
    if (r + 1 < 4) {
      u16* bufw = stage[(r + 1) & 1];
      *(uint4*)&bufw[sA ] = rA;
      *(uint4*)&bufw[sB0] = rne8(b00,b01);
      *(uint4*)&bufw[sB1] = rne8(b10,b11);
      if (r + 2 < 4) {
        const int o = (r + 2) * 32;
        rA = *(const uint4*)(Ag + o);
        b00 = *(const float4*)(B0 + o); b01 = *(const float4*)(B0 + o + 4);
        b10 = *(const float4*)(B1 + o); b11 = *(const float4*)(B1 + o + 4);
      }
    }
    MFMA1(acc);
  }

  __syncthreads();
  {
    const int r0 = (lane>>4)<<2;
    const int c0 = wc*32 + (lane&15);
#pragma unroll
    for (int i = 0; i < 2; ++i)
#pragma unroll
      for (int j = 0; j < 2; ++j)
#pragma unroll
        for (int g = 0; g < 4; ++g)
          fbuf[kgw*2176 + (r0 + i*16 + g)*68 + c0 + j*16] = acc[i][j][g];
  }
  __syncthreads();
  const int erow = wave << 2;
  const float b = bo[nBase + lane];
#pragma unroll
  for (int r = 0; r < 4; ++r) {
    const int row = erow + r;
    float e = fbuf[row*68 + lane] + fbuf[2176 + row*68 + lane]
            + fbuf[4352 + row*68 + lane] + fbuf[6528 + row*68 + lane];
    out[(size_t)(mBase+row)*D_TOT + nBase + lane] = e + b;
  }
}

extern "C" void kernel_launch(void* const* d_in, const int* in_sizes, int n_in,
                              void* d_out, int out_size, void* d_ws, size_t ws_size,
                              hipStream_t stream)
{
  const float* x   = (const float*)d_in[0];
  const float* wq  = (const float*)d_in[1];
  const float* bq  = (const float*)d_in[2];
  const float* wk  = (const float*)d_in[3];
  const float* bk  = (const float*)d_in[4];
  const float* wv  = (const float*)d_in[5];
  const float* bv  = (const float*)d_in[6];
  const float* wo  = (const float*)d_in[7];
  const float* bo  = (const float*)d_in[8];
  const float* alpha_u = (const float*)d_in[9];
  float* out = (float*)d_out;

  u16* U = (u16*)d_ws;
  u16* Qch   = U + 0;
  u16* Kch   = U + 524288;
  u16* vTh   = U + 1048576;
  u16* Eh    = U + 1572864;
  u16* out1h = U + 2621440;
  float* F = (float*)(U + 3145728);
  float* qnpart  = F;
  float* knpart  = F + 8192;
  float* uh2a    = F + 16384;
  float* vh2a    = F + 17408;
  float* rowpart = F + 18432;

  qkv_mfma<<<dim3(8,16,3), 512, 0, stream>>>(x, wq,bq, wk,bk, wv,bv,
      Qch, Kch, vTh, qnpart, knpart, uh2a, vh2a);
  score_mfma<<<dim3(16,16), 512, 0, stream>>>(Qch, Kch,
      qnpart, knpart, uh2a, vh2a, alpha_u, Eh, rowpart);
  av_mfma<<<dim3(8,32), 512, 0, stream>>>(Eh, vTh, rowpart, out1h);
  final_mfma<<<dim3(8,32), 512, 0, stream>>>(out1h, wo, bo, out);
}